// Round 1
// baseline (170.060 us; speedup 1.0000x reference)
//
#include <hip/hip_runtime.h>

// IIR biquad cascade (K=4), B=64, C=2, L=131072 -> 128 independent rows.
// Chunked warm-up parallelization: one lane per S-sample chunk, each lane
// warm-starts W samples early from zero state (poles r<=0.95 => truncation
// error ~poly(W)*0.95^W ~ 1e-9 at W=384; exact at row starts).
// Input/output staged through LDS with +1-padded stride so compute-side
// scalar LDS accesses are bank-conflict-free while global accesses stay
// coalesced float4.

#define SS   128   // output samples per lane (chunk size)
#define WW   384   // warm-up samples (zero-state spin-up)
#define TT   32    // time-tile staged per LDS round
#define TPB  256   // threads per block (= chunks per block)
#define LSTR 33    // LDS row stride in floats (odd => conflict-free)
#define KB   4     // biquads in cascade

__global__ __launch_bounds__(TPB) void iir_chunks_kernel(
    const float* __restrict__ x, const float* __restrict__ Bs,
    const float* __restrict__ As, float* __restrict__ out, int L)
{
    __shared__ float lds[TPB * LSTR];
    const int tid = threadIdx.x;
    const int bpr = (L / SS) / TPB;              // blocks per row (4)
    const int row = blockIdx.x / bpr;            // 0..127
    const int chunk0 = (blockIdx.x % bpr) * TPB; // first chunk of this block

    // ---- per-row coefficients (broadcast loads, all lanes same row) ----
    float b0[KB], b1[KB], b2[KB], na1[KB], na2[KB];
    const float* Bp = Bs + (size_t)row * KB * 3;
    const float* Ap = As + (size_t)row * KB * 3;
#pragma unroll
    for (int k = 0; k < KB; ++k) {
        float inv = 1.0f / Ap[3 * k];            // a0 == 1.0 in this problem
        b0[k]  =  Bp[3 * k]     * inv;
        b1[k]  =  Bp[3 * k + 1] * inv;
        b2[k]  =  Bp[3 * k + 2] * inv;
        na1[k] = -Ap[3 * k + 1] * inv;
        na2[k] = -Ap[3 * k + 2] * inv;
    }

    float s1[KB] = {0.f, 0.f, 0.f, 0.f};
    float s2[KB] = {0.f, 0.f, 0.f, 0.f};

    const float* xrow = x   + (size_t)row * L;
    float*       orow = out + (size_t)row * L;
    float*       myrow = lds + tid * LSTR;

    const int NT = (SS + WW) / TT;  // 16 tiles total
    const int WT = WW / TT;         // 12 warm tiles (no output)

#pragma unroll 1
    for (int it = 0; it < NT; ++it) {
        const int i0 = it * TT - WW;  // tile offset relative to chunk start

        // ---- cooperative coalesced load: global -> LDS ----
#pragma unroll
        for (int l = 0; l < (TPB * TT / 4) / TPB; ++l) {   // 8 float4s/thread
            int e  = l * TPB + tid;
            int j  = e >> 3;              // chunk slot 0..255 (TT/4 = 8)
            int p4 = (e & 7) << 2;        // float offset within tile
            int pos = (chunk0 + j) * SS + i0 + p4;  // position within row
            float4 v = make_float4(0.f, 0.f, 0.f, 0.f);
            if (pos >= 0) v = *reinterpret_cast<const float4*>(xrow + pos);
            float* d = lds + j * LSTR + p4;
            d[0] = v.x; d[1] = v.y; d[2] = v.z; d[3] = v.w;
        }
        __syncthreads();

        if (it < WT) {
            // ---- warm-up tile: advance state only ----
#pragma unroll
            for (int p = 0; p < TT; ++p) {
                float u = myrow[p];
#pragma unroll
                for (int k = 0; k < KB; ++k) {
                    float yv = fmaf(b0[k], u, s1[k]);
                    s1[k] = fmaf(na1[k], yv, fmaf(b1[k], u, s2[k]));
                    s2[k] = fmaf(na2[k], yv, b2[k] * u);
                    u = yv;
                }
            }
            __syncthreads();  // protect LDS before next tile's load
        } else {
            // ---- output tile: compute and write y back into LDS ----
#pragma unroll
            for (int p = 0; p < TT; ++p) {
                float u = myrow[p];
#pragma unroll
                for (int k = 0; k < KB; ++k) {
                    float yv = fmaf(b0[k], u, s1[k]);
                    s1[k] = fmaf(na1[k], yv, fmaf(b1[k], u, s2[k]));
                    s2[k] = fmaf(na2[k], yv, b2[k] * u);
                    u = yv;
                }
                myrow[p] = u;
            }
            __syncthreads();

            // ---- cooperative coalesced store: LDS -> global ----
#pragma unroll
            for (int l = 0; l < 8; ++l) {
                int e  = l * TPB + tid;
                int j  = e >> 3;
                int p4 = (e & 7) << 2;
                int pos = (chunk0 + j) * SS + i0 + p4;  // >= 0 in output tiles
                const float* sp = lds + j * LSTR + p4;
                float4 v = make_float4(sp[0], sp[1], sp[2], sp[3]);
                *reinterpret_cast<float4*>(orow + pos) = v;
            }
            __syncthreads();
        }
    }
}

extern "C" void kernel_launch(void* const* d_in, const int* in_sizes, int n_in,
                              void* d_out, int out_size, void* d_ws, size_t ws_size,
                              hipStream_t stream) {
    const float* x  = (const float*)d_in[0];   // (B, C, L) f32
    const float* Bs = (const float*)d_in[1];   // (B, C, K, 3) f32
    const float* As = (const float*)d_in[2];   // (B, C, K, 3) f32
    float* out = (float*)d_out;                // (B, C, L) f32

    const int rows = in_sizes[1] / (KB * 3);   // B*C = 128
    const int L    = in_sizes[0] / rows;       // 131072
    const int bpr  = (L / SS) / TPB;           // 4 blocks per row
    dim3 grid(rows * bpr), block(TPB);
    hipLaunchKernelGGL(iir_chunks_kernel, grid, block, 0, stream,
                       x, Bs, As, out, L);
}